// Round 11
// baseline (4670.519 us; speedup 1.0000x reference)
//
#include <hip/hip_runtime.h>
#include <math.h>

#define IN_DIM 16
#define HIDN 128
#define NH 8
#define DHD 16
#define NTYPE 12
#define NLAYERS 4
#define NPG 5000
#define NSEGP 250
#define RPS (NPG / NSEGP)
#define C1 656
#define C2 1312
#define C1Q (C1 / 4)
#define CAP 128
#define NPW 4
#define HREG (NPG / 2)            // 2500 rows per (graph,half) region
#define EDGE_SLOTS (HREG / NPW)   // 625
#define NBLK 1024
#define NTHR 256
#define NTOT (NBLK * NTHR)
#define TPR ((HREG + 15) / 16)    // 157 gemm tiles (16 rows) per region
#define SMEM_BYTES 19072

__device__ __forceinline__ float gelu_t(float x) {
    float x3 = x * x * x;
    float u = 0.7978845608028654f * (x + 0.044715f * x3);
    return 0.5f * x * (1.0f + tanhf(u));
}

__device__ __forceinline__ unsigned pack_bf16(float lo, float hi) {
    unsigned a = __float_as_uint(lo);
    unsigned b = __float_as_uint(hi);
    a = (a + 0x7fffu + ((a >> 16) & 1u)) >> 16;
    b = (b + 0x7fffu + ((b >> 16) & 1u)) & 0xffff0000u;
    return a | b;
}

__device__ __forceinline__ float lrelu(float x) { return (x >= 0.f) ? x : 0.2f * x; }

// global barrier: monotone counter, all NBLK blocks co-resident by capacity
__device__ __forceinline__ void gbar(int* bar, int target) {
    __syncthreads();
    __threadfence();   // release: make this block's writes visible device-wide
    if (threadIdx.x == 0) {
        __hip_atomic_fetch_add(bar, 1, __ATOMIC_ACQ_REL, __HIP_MEMORY_SCOPE_AGENT);
        while (__hip_atomic_load(bar, __ATOMIC_ACQUIRE, __HIP_MEMORY_SCOPE_AGENT) < target)
            __builtin_amdgcn_s_sleep(32);
    }
    __syncthreads();
    __threadfence();   // acquire: invalidate stale cache lines before reads
}

// ---- init: ea table + zero cursors + barrier state (separate tiny dispatch) ----
__global__ __launch_bounds__(256) void k_init(const float* __restrict__ etab,
                                              const float* __restrict__ aed,
                                              float* __restrict__ ea, int* __restrict__ c1,
                                              int* __restrict__ c2, int* __restrict__ bar,
                                              int N) {
    int i = blockIdx.x * 256 + threadIdx.x;
    if (i < NTYPE * NH) {
        int t = i / NH, hh = i % NH;
        float s = 0.f;
        #pragma unroll
        for (int d = 0; d < DHD; d++) s += etab[t * HIDN + hh * DHD + d] * aed[hh * DHD + d];
        ea[i] = s;
    }
    if (i < N) {
        c1[i] = 0;
        c2[i] = 0;
    }
    if (i == 0) bar[0] = 0;
}

// ---- persistent mega-kernel: CSR + embed + 4x(gemm,edge) + pool + bcast ----
__global__ __launch_bounds__(NTHR, 4) void k_mega(
    const float* __restrict__ feat, const float* __restrict__ We,
    const float* __restrict__ be, const float* __restrict__ W,
    const float* __restrict__ asf, const float* __restrict__ adf,
    const float* __restrict__ ea, const int* __restrict__ srcp,
    const int* __restrict__ dstp, const int* __restrict__ etp,
    float* __restrict__ h, unsigned* __restrict__ z16, float* __restrict__ slog,
    float* __restrict__ dlog, int* __restrict__ rowptr, int* __restrict__ cnt,
    int* __restrict__ cur2, unsigned* __restrict__ payload, int* __restrict__ bsum,
    int* __restrict__ bpre, float* __restrict__ gpart, float* __restrict__ gemb,
    int* __restrict__ bar, float* __restrict__ out, int N, int E) {
    __shared__ __align__(16) char smem[SMEM_BYTES];
    const int bid = blockIdx.x;
    const int tid = threadIdx.x;
    const int gtid = bid * NTHR + tid;
    const int wave = tid >> 6, lane = tid & 63;
    int ph = 0;

    // ---- P1: degree count + embed ----
    for (int e = gtid; e < E; e += NTOT) atomicAdd(&cnt[dstp[e]], 1);
    {
        for (int u = bid; u < NPG; u += NBLK) {   // N/NPW = 5000 units, 4 waves each
            int n = u * NPW + wave;
            float v = 0.f;
            if (lane < IN_DIM) {
                v = feat[n * IN_DIM + lane];
                if ((lane >= 2 && lane < 4) || lane >= 10) v = 0.f;
                out[(size_t)n * C2 + lane] = v;
            }
            float a0 = be[lane], a1 = be[lane + 64];
            #pragma unroll
            for (int k = 0; k < IN_DIM; k++) {
                float fk = __shfl(v, k);
                a0 += fk * We[k * HIDN + lane];
                a1 += fk * We[k * HIDN + lane + 64];
            }
            float g0 = gelu_t(a0), g1 = gelu_t(a1);
            size_t hb = (size_t)n * HIDN;
            h[hb + lane] = g0;
            h[hb + lane + 64] = g1;
            size_t ob = (size_t)n * C2 + IN_DIM;
            out[ob + lane] = g0;
            out[ob + lane + 64] = g1;
        }
    }
    gbar(bar, (++ph) * NBLK);

    // ---- P2a: per-block chunk sums ----
    {
        int lo = bid * 20, hi = lo + 20;
        if (hi > N) hi = N;
        if (tid == 0) {
            int s = 0;
            for (int i = lo; i < hi; i++) s += cnt[i];
            bsum[bid] = s;
        }
    }
    gbar(bar, (++ph) * NBLK);

    // ---- P2b: block 0 scans the 1024 block sums ----
    if (bid == 0) {
        int* sb = (int*)smem;            // 1024 ints
        int* ps = (int*)(smem + 4096);   // 256 ints
        for (int i = tid; i < NBLK; i += NTHR) sb[i] = bsum[i];
        __syncthreads();
        int bi = tid * 4;
        int a0 = sb[bi], a1 = sb[bi + 1], a2 = sb[bi + 2], a3 = sb[bi + 3];
        int tsum = a0 + a1 + a2 + a3;
        ps[tid] = tsum;
        __syncthreads();
        for (int off = 1; off < NTHR; off <<= 1) {
            int v = (tid >= off) ? ps[tid - off] : 0;
            __syncthreads();
            ps[tid] += v;
            __syncthreads();
        }
        int run = (tid == 0) ? 0 : ps[tid - 1];
        bpre[bi] = run;
        bpre[bi + 1] = run + a0;
        bpre[bi + 2] = run + a0 + a1;
        bpre[bi + 3] = run + a0 + a1 + a2;
        if (tid == NTHR - 1) rowptr[N] = run + tsum;
    }
    gbar(bar, (++ph) * NBLK);

    // ---- P2c: write rowptr for own chunk ----
    {
        int lo = bid * 20, hi = lo + 20;
        if (hi > N) hi = N;
        if (tid == 0 && lo < N) {
            int run = bpre[bid];
            for (int i = lo; i < hi; i++) {
                rowptr[i] = run;
                run += cnt[i];
            }
        }
    }
    gbar(bar, (++ph) * NBLK);

    // ---- P3: scatter ----
    for (int e = gtid; e < E; e += NTOT) {
        int d = dstp[e];
        int pos = rowptr[d] + atomicAdd(&cur2[d], 1);
        payload[pos] = (unsigned)srcp[e] | ((unsigned)etp[e] << 16);
    }
    gbar(bar, (++ph) * NBLK);

    // region mapping (fixed per block)
    const int xcd = bid & 7, g = xcd & 3, half = xcd >> 2;
    const int rbase = g * NPG + half * HREG;
    const int rend = rbase + HREG;
    const int cg = tid & 15;
    const int c0 = cg * 8;
    const float4 as0 = *(const float4*)&asf[c0];
    const float4 as1 = *(const float4*)&asf[c0 + 4];
    const float4 ad0 = *(const float4*)&adf[c0];
    const float4 ad1 = *(const float4*)&adf[c0 + 4];

    // ---- layers ----
    for (int l = 0; l < NLAYERS; l++) {
        // GEMM phase: 16-row tiles, KC=32
        {
            float* Wc = (float*)smem;              // [32][128]
            float* hcb = (float*)(smem + 16384);   // [16][36]
            const int rg = tid >> 4;               // row 0..15
            for (int s = bid >> 3; s < TPR; s += 128) {
                int n0 = rbase + s * 16;
                float acc[8];
                #pragma unroll
                for (int j = 0; j < 8; j++) acc[j] = 0.f;
                for (int k0 = 0; k0 < HIDN; k0 += 32) {
                    for (int i = tid; i < 32 * 32; i += NTHR) {
                        int kk = i >> 5, cc = (i & 31) << 2;
                        *(float4*)&Wc[kk * HIDN + cc] = *(const float4*)&W[(k0 + kk) * HIDN + cc];
                    }
                    {
                        int row = tid >> 4, col2 = (tid & 15) * 2;
                        int n = n0 + row;
                        float2 v = make_float2(0.f, 0.f);
                        if (n < rend) v = *(const float2*)&h[(size_t)n * HIDN + k0 + col2];
                        hcb[row * 36 + col2] = v.x;
                        hcb[row * 36 + col2 + 1] = v.y;
                    }
                    __syncthreads();
                    #pragma unroll
                    for (int k = 0; k < 32; k++) {
                        float4 w0 = *(float4*)&Wc[k * HIDN + c0];
                        float4 w1 = *(float4*)&Wc[k * HIDN + c0 + 4];
                        float hv = hcb[rg * 36 + k];
                        acc[0] += hv * w0.x;
                        acc[1] += hv * w0.y;
                        acc[2] += hv * w0.z;
                        acc[3] += hv * w0.w;
                        acc[4] += hv * w1.x;
                        acc[5] += hv * w1.y;
                        acc[6] += hv * w1.z;
                        acc[7] += hv * w1.w;
                    }
                    __syncthreads();
                }
                int n = n0 + rg;
                float ps = acc[0] * as0.x + acc[1] * as0.y + acc[2] * as0.z + acc[3] * as0.w +
                           acc[4] * as1.x + acc[5] * as1.y + acc[6] * as1.z + acc[7] * as1.w;
                float pd = acc[0] * ad0.x + acc[1] * ad0.y + acc[2] * ad0.z + acc[3] * ad0.w +
                           acc[4] * ad1.x + acc[5] * ad1.y + acc[6] * ad1.z + acc[7] * ad1.w;
                ps += __shfl_xor(ps, 1);
                pd += __shfl_xor(pd, 1);
                unsigned u[8];
                #pragma unroll
                for (int j = 0; j < 8; j++) {
                    float other = __shfl_xor(acc[j], 8);
                    u[j] = pack_bf16(acc[j], other);
                }
                if (n < rend) {
                    if (cg < 8) {
                        *(uint4*)&z16[(size_t)n * 64 + c0] = make_uint4(u[0], u[1], u[2], u[3]);
                        *(uint4*)&z16[(size_t)n * 64 + c0 + 4] = make_uint4(u[4], u[5], u[6], u[7]);
                    }
                    if ((cg & 1) == 0) {
                        slog[n * NH + (cg >> 1)] = ps;
                        dlog[n * NH + (cg >> 1)] = pd;
                    }
                }
            }
        }
        gbar(bar, (++ph) * NBLK);

        // EDGE phase
        {
            float* lbuf = (float*)smem;                     // [4][CAP*NH]
            unsigned* pbuf = (unsigned*)(smem + 16384);     // [4][CAP]
            float* dl = (float*)(smem + 18432);             // [4][NH]
            float* red = (float*)(smem + 18560);            // [4][NH]
            float* sea = (float*)(smem + 18688);            // [NTYPE*NH]
            if (tid < NTYPE * NH) sea[tid] = ea[tid];
            float* lb = lbuf + wave * (CAP * NH);
            unsigned* pb = pbuf + wave * CAP;
            int colbase = IN_DIM + HIDN * (l + 1);
            for (int s = bid >> 3; s < EDGE_SLOTS; s += 128) {
                int unit = g * (NPG / NPW) + half * EDGE_SLOTS + s;
                int n = unit * NPW + wave;
                int rs = rowptr[n], re = rowptr[n + 1];
                int cntE = re - rs;
                if (cntE > CAP) cntE = CAP;
                if (lane < NH) dl[wave * NH + lane] = dlog[n * NH + lane];
                for (int e = lane; e < cntE; e += 64) pb[e] = payload[rs + e];
                __syncthreads();

                int o = lane & 1;
                int eoff = lane >> 1;
                float4 dl4 = *(float4*)&dl[wave * NH + o * 4];
                float4 ssum4 = make_float4(0.f, 0.f, 0.f, 0.f);
                for (int base = 0; base < cntE; base += 32) {
                    int el = base + eoff;
                    if (el < cntE) {
                        unsigned pk = pb[el];
                        int src = pk & 0xffff;
                        int et = pk >> 16;
                        float4 s4 = *(const float4*)&slog[src * NH + o * 4];
                        float4 e4 = *(float4*)&sea[et * NH + o * 4];
                        float4 ex;
                        ex.x = __expf(lrelu(s4.x + dl4.x + e4.x));
                        ex.y = __expf(lrelu(s4.y + dl4.y + e4.y));
                        ex.z = __expf(lrelu(s4.z + dl4.z + e4.z));
                        ex.w = __expf(lrelu(s4.w + dl4.w + e4.w));
                        *(float4*)&lb[el * NH + o * 4] = ex;
                        ssum4.x += ex.x;
                        ssum4.y += ex.y;
                        ssum4.z += ex.z;
                        ssum4.w += ex.w;
                    }
                }
                #pragma unroll
                for (int m = 2; m <= 32; m <<= 1) {
                    ssum4.x += __shfl_xor(ssum4.x, m);
                    ssum4.y += __shfl_xor(ssum4.y, m);
                    ssum4.z += __shfl_xor(ssum4.z, m);
                    ssum4.w += __shfl_xor(ssum4.w, m);
                }
                if (lane < 2) {
                    float4 r4;
                    r4.x = 1.0f / (ssum4.x + 1e-9f);
                    r4.y = 1.0f / (ssum4.y + 1e-9f);
                    r4.z = 1.0f / (ssum4.z + 1e-9f);
                    r4.w = 1.0f / (ssum4.w + 1e-9f);
                    *(float4*)&red[wave * NH + o * 4] = r4;
                }
                __syncthreads();

                int h1 = lane >> 4, h2 = h1 + 4;
                float r1 = red[wave * NH + h1], r2 = red[wave * NH + h2];
                float a0 = 0.f, a1 = 0.f;
                int e = 0;
                for (; e + 7 < cntE; e += 8) {
                    unsigned v[8];
                    #pragma unroll
                    for (int j = 0; j < 8; j++) {
                        unsigned sidx = pb[e + j] & 0xffff;
                        v[j] = z16[(size_t)sidx * 64 + lane];
                    }
                    #pragma unroll
                    for (int j = 0; j < 8; j++) {
                        float l0 = lb[(e + j) * NH + h1];
                        float l1 = lb[(e + j) * NH + h2];
                        a0 += l0 * __uint_as_float(v[j] << 16);
                        a1 += l1 * __uint_as_float(v[j] & 0xffff0000u);
                    }
                }
                for (; e < cntE; e++) {
                    unsigned sidx = pb[e] & 0xffff;
                    unsigned v0 = z16[(size_t)sidx * 64 + lane];
                    a0 += lb[e * NH + h1] * __uint_as_float(v0 << 16);
                    a1 += lb[e * NH + h2] * __uint_as_float(v0 & 0xffff0000u);
                }
                a0 *= r1;
                a1 *= r2;
                size_t hb = (size_t)n * HIDN;
                float o0 = h[hb + lane] + gelu_t(a0);
                float o1 = h[hb + lane + 64] + gelu_t(a1);
                h[hb + lane] = o0;
                h[hb + lane + 64] = o1;
                size_t ob = (size_t)n * C2 + colbase;
                out[ob + lane] = o0;
                out[ob + lane + 64] = o1;
                __syncthreads();   // protect pbuf/lbuf before next unit
            }
        }
        gbar(bar, (++ph) * NBLK);
    }

    // ---- pool partial ----
    for (int sg = bid; sg < 4 * NSEGP; sg += NBLK) {
        int b = sg / NSEGP, seg = sg % NSEGP;
        int n0 = b * NPG + seg * RPS;
        for (int c = tid; c < C1; c += NTHR) {
            float m = -3.4e38f;
            #pragma unroll
            for (int i = 0; i < RPS; i++) m = fmaxf(m, out[(size_t)(n0 + i) * C2 + c]);
            gpart[(size_t)sg * C1 + c] = m;
        }
    }
    gbar(bar, (++ph) * NBLK);

    // ---- pool final ----
    for (int j = gtid; j < 4 * C1; j += NTOT) {
        int b = j / C1, c = j % C1;
        float m = -3.4e38f;
        for (int s = 0; s < NSEGP; s++) m = fmaxf(m, gpart[(size_t)(b * NSEGP + s) * C1 + c]);
        gemb[j] = m;
    }
    gbar(bar, (++ph) * NBLK);

    // ---- broadcast ----
    for (size_t idx = gtid; idx < (size_t)N * C1Q; idx += NTOT) {
        int n = idx / C1Q, c4 = idx % C1Q;
        int b = n / NPG;
        float4 gv = *(const float4*)&gemb[b * C1 + c4 * 4];
        *(float4*)&out[(size_t)n * C2 + C1 + c4 * 4] = gv;
    }
}

extern "C" void kernel_launch(void* const* d_in, const int* in_sizes, int n_in, void* d_out,
                              int out_size, void* d_ws, size_t ws_size, hipStream_t stream) {
    const float* feat = (const float*)d_in[0];
    const float* etab = (const float*)d_in[1];
    const float* We = (const float*)d_in[2];
    const float* be = (const float*)d_in[3];
    const float* Wc = (const float*)d_in[4];
    const float* a_src = (const float*)d_in[5];
    const float* a_dst = (const float*)d_in[6];
    const float* a_edge = (const float*)d_in[7];
    const int* eidx = (const int*)d_in[8];
    const int* etype = (const int*)d_in[9];
    float* out = (float*)d_out;

    const int N = in_sizes[0] / IN_DIM;   // 20000
    const int E = in_sizes[9];            // 660000

    const int* srcp = eidx;
    const int* dstp = eidx + E;

    char* w = (char*)d_ws;
    size_t off = 0;
    auto carve = [&](size_t bytes) {
        char* p = w + off;
        off = (off + bytes + 255) & ~(size_t)255;
        return p;
    };
    float* h = (float*)carve((size_t)N * HIDN * 4);
    unsigned* z16 = (unsigned*)carve((size_t)N * 64 * 4);
    float* slog = (float*)carve((size_t)N * NH * 4);
    float* dlog = (float*)carve((size_t)N * NH * 4);
    float* ea = (float*)carve(NTYPE * NH * 4);
    int* rowptr = (int*)carve((size_t)(N + 1) * 4);
    int* cursor = (int*)carve((size_t)N * 4);
    int* cursor2 = (int*)carve((size_t)N * 4);
    unsigned* payload = (unsigned*)carve((size_t)E * 4);
    int* bsum = (int*)carve(NBLK * 4);
    int* bpre = (int*)carve(NBLK * 4);
    float* gpart = (float*)carve((size_t)4 * NSEGP * C1 * 4);
    float* gemb = (float*)carve((size_t)4 * C1 * 4);
    int* bar = (int*)carve(256);
    (void)ws_size;

    k_init<<<(N + 255) / 256, 256, 0, stream>>>(etab, a_edge, ea, cursor, cursor2, bar, N);
    k_mega<<<NBLK, NTHR, 0, stream>>>(feat, We, be, Wc, a_src, a_dst, ea, srcp, dstp, etype,
                                      h, z16, slog, dlog, rowptr, cursor, cursor2, payload,
                                      bsum, bpre, gpart, gemb, bar, out, N, E);
}

// Round 12
// 253.835 us; speedup vs baseline: 18.3998x; 18.3998x over previous
//
#include <hip/hip_runtime.h>
#include <math.h>

#define IN_DIM 16
#define HIDN 128
#define NH 8
#define DHD 16
#define NTYPE 12
#define NLAYERS 4
#define NPG 5000
#define NSEGP 250
#define RPS (NPG / NSEGP)
#define C1 656
#define C2 1312
#define C1Q (C1 / 4)
#define CAP 64              // fixed bucket slots per node (P(deg>64) ~ e^-97)
#define NPW 4
#define HREG (NPG / 2)
#define GEMM_SLOTS ((HREG + 63) / 64)   // 40
#define EDGE_SLOTS (HREG / NPW)         // 625

__device__ __forceinline__ float gelu_t(float x) {
    float x3 = x * x * x;
    float u = 0.7978845608028654f * (x + 0.044715f * x3);
    return 0.5f * x * (1.0f + tanhf(u));
}

__device__ __forceinline__ unsigned pack_bf16(float lo, float hi) {
    unsigned a = __float_as_uint(lo);
    unsigned b = __float_as_uint(hi);
    a = (a + 0x7fffu + ((a >> 16) & 1u)) >> 16;
    b = (b + 0x7fffu + ((b >> 16) & 1u)) & 0xffff0000u;
    return a | b;
}

__device__ __forceinline__ float lrelu(float x) { return (x >= 0.f) ? x : 0.2f * x; }

// ---- init: ea table + zero bucket counters ----
__global__ __launch_bounds__(256) void k_init(const float* __restrict__ etab,
                                              const float* __restrict__ aed,
                                              float* __restrict__ ea, int* __restrict__ cnt,
                                              int N) {
    int i = blockIdx.x * 256 + threadIdx.x;
    if (i < NTYPE * NH) {
        int t = i / NH, hh = i % NH;
        float s = 0.f;
        #pragma unroll
        for (int d = 0; d < DHD; d++) s += etab[t * HIDN + hh * DHD + d] * aed[hh * DHD + d];
        ea[i] = s;
    }
    if (i < N) cnt[i] = 0;
}

// ---- embed ----
__global__ __launch_bounds__(128) void k_embed(const float* __restrict__ feat,
                                               const float* __restrict__ We,
                                               const float* __restrict__ be,
                                               float* __restrict__ h, float* __restrict__ out,
                                               int N) {
    int n = blockIdx.x;
    int c = threadIdx.x;
    __shared__ float f[IN_DIM];
    if (c < IN_DIM) {
        float v = feat[n * IN_DIM + c];
        if ((c >= 2 && c < 4) || c >= 10) v = 0.f;
        f[c] = v;
        out[(size_t)n * C2 + c] = v;
    }
    __syncthreads();
    float a = be[c];
    #pragma unroll
    for (int k = 0; k < IN_DIM; k++) a += f[k] * We[k * HIDN + c];
    float g = gelu_t(a);
    h[(size_t)n * HIDN + c] = g;
    out[(size_t)n * C2 + IN_DIM + c] = g;
}

// ---- direct bucketing: payload2[d*64 + slot] (replaces count+scan+scatter) ----
__global__ void k_bucket(const int* __restrict__ srcp, const int* __restrict__ dstp,
                         const int* __restrict__ etp, int* __restrict__ cnt,
                         unsigned* __restrict__ payload2, int E) {
    int e = blockIdx.x * 256 + threadIdx.x;
    if (e < E) {
        int d = dstp[e];
        int slot = atomicAdd(&cnt[d], 1);
        if (slot < CAP)
            payload2[(size_t)d * CAP + slot] = (unsigned)srcp[e] | ((unsigned)etp[e] << 16);
    }
}

// ---- per-layer GEMM: 64-row tiles, XCD-region mapped; bank-fixed row mapping ----
#define KC 64
__global__ __launch_bounds__(256) void k_gemm(const float* __restrict__ h,
                                              const float* __restrict__ W,
                                              const float* __restrict__ asf,
                                              const float* __restrict__ adf,
                                              unsigned* __restrict__ z16,
                                              float* __restrict__ slog,
                                              float* __restrict__ dlog, int N) {
    __shared__ float Wc[KC][HIDN];
    __shared__ float hc[64][KC + 4];
    int xcd = blockIdx.x & 7, slot = blockIdx.x >> 3;
    int g = xcd & 3, half = xcd >> 2;
    int base = g * NPG + half * HREG;
    int rend = base + HREG;
    int n0 = base + slot * 64;
    int t = threadIdx.x;
    int cg = t & 15, rg = t >> 4;
    int c0 = cg * 8;
    float acc[4][8];
    #pragma unroll
    for (int i = 0; i < 4; i++)
        #pragma unroll
        for (int j = 0; j < 8; j++) acc[i][j] = 0.f;

    for (int k0 = 0; k0 < HIDN; k0 += KC) {
        for (int i = t; i < KC * 32; i += 256) {
            int kk = i >> 5, cc = (i & 31) << 2;
            *(float4*)&Wc[kk][cc] = *(const float4*)&W[(k0 + kk) * HIDN + cc];
        }
        for (int i = t; i < 64 * (KC / 4); i += 256) {
            int rr = i / (KC / 4), kk = (i % (KC / 4)) * 4;
            int n = n0 + rr;
            float4 v = make_float4(0.f, 0.f, 0.f, 0.f);
            if (n < rend) v = *(const float4*)&h[(size_t)n * HIDN + k0 + kk];
            *(float4*)&hc[rr][kk] = v;
        }
        __syncthreads();
        for (int k = 0; k < KC; k++) {
            float4 w0 = *(float4*)&Wc[k][c0];
            float4 w1 = *(float4*)&Wc[k][c0 + 4];
            float hv[4];
            // row = rg + 16*i: bank (rg*4+k)%32 -> 2-way (free); rg*4+i was 8-way
            #pragma unroll
            for (int i = 0; i < 4; i++) hv[i] = hc[rg + 16 * i][k];
            #pragma unroll
            for (int i = 0; i < 4; i++) {
                acc[i][0] += hv[i] * w0.x;
                acc[i][1] += hv[i] * w0.y;
                acc[i][2] += hv[i] * w0.z;
                acc[i][3] += hv[i] * w0.w;
                acc[i][4] += hv[i] * w1.x;
                acc[i][5] += hv[i] * w1.y;
                acc[i][6] += hv[i] * w1.z;
                acc[i][7] += hv[i] * w1.w;
            }
        }
        __syncthreads();
    }
    float4 s0 = *(const float4*)&asf[c0];
    float4 s1 = *(const float4*)&asf[c0 + 4];
    float4 d0 = *(const float4*)&adf[c0];
    float4 d1 = *(const float4*)&adf[c0 + 4];
    #pragma unroll
    for (int i = 0; i < 4; i++) {
        int n = n0 + rg + 16 * i;
        float ps = acc[i][0] * s0.x + acc[i][1] * s0.y + acc[i][2] * s0.z + acc[i][3] * s0.w +
                   acc[i][4] * s1.x + acc[i][5] * s1.y + acc[i][6] * s1.z + acc[i][7] * s1.w;
        float pd = acc[i][0] * d0.x + acc[i][1] * d0.y + acc[i][2] * d0.z + acc[i][3] * d0.w +
                   acc[i][4] * d1.x + acc[i][5] * d1.y + acc[i][6] * d1.z + acc[i][7] * d1.w;
        ps += __shfl_xor(ps, 1);
        pd += __shfl_xor(pd, 1);
        unsigned u[8];
        #pragma unroll
        for (int j = 0; j < 8; j++) {
            float other = __shfl_xor(acc[i][j], 8);
            u[j] = pack_bf16(acc[i][j], other);
        }
        if (n < rend) {
            if (cg < 8) {
                *(uint4*)&z16[(size_t)n * 64 + c0] = make_uint4(u[0], u[1], u[2], u[3]);
                *(uint4*)&z16[(size_t)n * 64 + c0 + 4] = make_uint4(u[4], u[5], u[6], u[7]);
            }
            if ((cg & 1) == 0) {
                slog[n * NH + (cg >> 1)] = ps;
                dlog[n * NH + (cg >> 1)] = pd;
            }
        }
    }
}

// ---- per-layer edge aggregation: bucketed payload, CAP=64 ----
__global__ __launch_bounds__(256) void k_edge(const int* __restrict__ cnt,
                                              const unsigned* __restrict__ payload2,
                                              const float* __restrict__ slog,
                                              const float* __restrict__ dlog,
                                              const float* __restrict__ ea,
                                              const unsigned* __restrict__ z16,
                                              float* __restrict__ h,
                                              float* __restrict__ out, int colbase, int N) {
    int wave = threadIdx.x >> 6, lane = threadIdx.x & 63;
    int xcd = blockIdx.x & 7, slot = blockIdx.x >> 3;
    int g = xcd & 3, half = xcd >> 2;
    int unit = g * (NPG / NPW) + half * EDGE_SLOTS + slot;
    int n = unit * NPW + wave;
    bool active = (n < N);
    __shared__ float lbuf[NPW][CAP * NH];
    __shared__ unsigned pbuf[NPW][CAP];
    __shared__ float dl[NPW][NH];
    __shared__ float red[NPW][NH];
    __shared__ float sea[NTYPE * NH];

    if (threadIdx.x < NTYPE * NH) sea[threadIdx.x] = ea[threadIdx.x];

    int cntE = 0;
    if (active) {
        cntE = cnt[n];
        if (cntE > CAP) cntE = CAP;
        if (lane < NH) dl[wave][lane] = dlog[n * NH + lane];
    }
    if (lane < cntE) pbuf[wave][lane] = payload2[(size_t)n * CAP + lane];
    __syncthreads();

    // fused: gather -> leaky -> exp -> lbuf + per-head sum (no-max softmax)
    int o = lane & 1;
    int eoff = lane >> 1;
    float4 dl4 = *(float4*)&dl[wave][o * 4];
    float4 ssum4 = make_float4(0.f, 0.f, 0.f, 0.f);
    #pragma unroll
    for (int base = 0; base < CAP; base += 32) {
        int el = base + eoff;
        if (el < cntE) {
            unsigned pk = pbuf[wave][el];
            int src = pk & 0xffff;
            int et = pk >> 16;
            float4 s4 = *(const float4*)&slog[src * NH + o * 4];
            float4 e4 = *(float4*)&sea[et * NH + o * 4];
            float4 ex;
            ex.x = __expf(lrelu(s4.x + dl4.x + e4.x));
            ex.y = __expf(lrelu(s4.y + dl4.y + e4.y));
            ex.z = __expf(lrelu(s4.z + dl4.z + e4.z));
            ex.w = __expf(lrelu(s4.w + dl4.w + e4.w));
            *(float4*)&lbuf[wave][el * NH + o * 4] = ex;
            ssum4.x += ex.x;
            ssum4.y += ex.y;
            ssum4.z += ex.z;
            ssum4.w += ex.w;
        }
    }
    #pragma unroll
    for (int m = 2; m <= 32; m <<= 1) {
        ssum4.x += __shfl_xor(ssum4.x, m);
        ssum4.y += __shfl_xor(ssum4.y, m);
        ssum4.z += __shfl_xor(ssum4.z, m);
        ssum4.w += __shfl_xor(ssum4.w, m);
    }
    if (lane < 2) {
        float4 r4;
        r4.x = 1.0f / (ssum4.x + 1e-9f);
        r4.y = 1.0f / (ssum4.y + 1e-9f);
        r4.z = 1.0f / (ssum4.z + 1e-9f);
        r4.w = 1.0f / (ssum4.w + 1e-9f);
        *(float4*)&red[wave][o * 4] = r4;
    }
    __syncthreads();

    // aggregation: lane owns cols (lane, lane+64) packed in one u32 per src row
    int h1 = lane >> 4, h2 = h1 + 4;
    float r1 = red[wave][h1], r2 = red[wave][h2];
    float a0 = 0.f, a1 = 0.f;
    int e = 0;
    for (; e + 7 < cntE; e += 8) {
        unsigned v[8];
        #pragma unroll
        for (int j = 0; j < 8; j++) {
            unsigned s = pbuf[wave][e + j] & 0xffff;
            v[j] = z16[(size_t)s * 64 + lane];
        }
        #pragma unroll
        for (int j = 0; j < 8; j++) {
            float l0 = lbuf[wave][(e + j) * NH + h1];
            float l1 = lbuf[wave][(e + j) * NH + h2];
            a0 += l0 * __uint_as_float(v[j] << 16);
            a1 += l1 * __uint_as_float(v[j] & 0xffff0000u);
        }
    }
    for (; e < cntE; e++) {
        unsigned s0 = pbuf[wave][e] & 0xffff;
        unsigned v0 = z16[(size_t)s0 * 64 + lane];
        a0 += lbuf[wave][e * NH + h1] * __uint_as_float(v0 << 16);
        a1 += lbuf[wave][e * NH + h2] * __uint_as_float(v0 & 0xffff0000u);
    }
    if (active) {
        a0 *= r1;
        a1 *= r2;
        size_t hb = (size_t)n * HIDN;
        float o0 = h[hb + lane] + gelu_t(a0);
        float o1 = h[hb + lane + 64] + gelu_t(a1);
        h[hb + lane] = o0;
        h[hb + lane + 64] = o1;
        size_t ob = (size_t)n * C2 + colbase;
        out[ob + lane] = o0;
        out[ob + lane + 64] = o1;
    }
}

// ---- graph max-pool ----
__global__ __launch_bounds__(256) void k_pool_partial(const float* __restrict__ out,
                                                      float* __restrict__ gpart) {
    int b = blockIdx.x / NSEGP, seg = blockIdx.x % NSEGP;
    int n0 = b * NPG + seg * RPS;
    for (int c = threadIdx.x; c < C1; c += 256) {
        float m = -3.4e38f;
        #pragma unroll
        for (int i = 0; i < RPS; i++) m = fmaxf(m, out[(size_t)(n0 + i) * C2 + c]);
        gpart[(size_t)(b * NSEGP + seg) * C1 + c] = m;
    }
}

// wave-per-output final reduction (was 250 serial loads/thread)
__global__ __launch_bounds__(256) void k_pool_final(const float* __restrict__ gpart,
                                                    float* __restrict__ gemb, int B) {
    int w = blockIdx.x * 4 + (threadIdx.x >> 6);
    int lane = threadIdx.x & 63;
    if (w >= B * C1) return;
    int b = w / C1, c = w % C1;
    float m = -3.4e38f;
    for (int s = lane; s < NSEGP; s += 64) m = fmaxf(m, gpart[(size_t)(b * NSEGP + s) * C1 + c]);
    #pragma unroll
    for (int k = 1; k < 64; k <<= 1) m = fmaxf(m, __shfl_xor(m, k));
    if (lane == 0) gemb[w] = m;
}

__global__ __launch_bounds__(256) void k_bcast(const float* __restrict__ gemb,
                                               float* __restrict__ out, int N) {
    int idx = blockIdx.x * 256 + threadIdx.x;
    if (idx < N * C1Q) {
        int n = idx / C1Q, c4 = idx % C1Q;
        int b = n / NPG;
        float4 g = *(const float4*)&gemb[b * C1 + c4 * 4];
        *(float4*)&out[(size_t)n * C2 + C1 + c4 * 4] = g;
    }
}

extern "C" void kernel_launch(void* const* d_in, const int* in_sizes, int n_in, void* d_out,
                              int out_size, void* d_ws, size_t ws_size, hipStream_t stream) {
    const float* feat = (const float*)d_in[0];
    const float* etab = (const float*)d_in[1];
    const float* We = (const float*)d_in[2];
    const float* be = (const float*)d_in[3];
    const float* Wc = (const float*)d_in[4];
    const float* a_src = (const float*)d_in[5];
    const float* a_dst = (const float*)d_in[6];
    const float* a_edge = (const float*)d_in[7];
    const int* eidx = (const int*)d_in[8];
    const int* etype = (const int*)d_in[9];
    float* out = (float*)d_out;

    const int N = in_sizes[0] / IN_DIM;   // 20000
    const int E = in_sizes[9];            // 660000
    const int B = N / NPG;                // 4

    const int* srcp = eidx;
    const int* dstp = eidx + E;

    char* w = (char*)d_ws;
    size_t off = 0;
    auto carve = [&](size_t bytes) {
        char* p = w + off;
        off = (off + bytes + 255) & ~(size_t)255;
        return p;
    };
    float* h = (float*)carve((size_t)N * HIDN * 4);
    unsigned* z16 = (unsigned*)carve((size_t)N * 64 * 4);
    float* slog = (float*)carve((size_t)N * NH * 4);
    float* dlog = (float*)carve((size_t)N * NH * 4);
    float* ea = (float*)carve(NTYPE * NH * 4);
    int* cnt = (int*)carve((size_t)N * 4);
    unsigned* payload2 = (unsigned*)carve((size_t)N * CAP * 4);
    float* gpart = (float*)carve((size_t)B * NSEGP * C1 * 4);
    float* gemb = (float*)carve((size_t)B * C1 * 4);
    (void)ws_size;

    k_init<<<(N + 255) / 256, 256, 0, stream>>>(etab, a_edge, ea, cnt, N);
    k_embed<<<N, 128, 0, stream>>>(feat, We, be, h, out, N);
    k_bucket<<<(E + 255) / 256, 256, 0, stream>>>(srcp, dstp, etype, cnt, payload2, E);

    for (int l = 0; l < NLAYERS; l++) {
        k_gemm<<<8 * GEMM_SLOTS, 256, 0, stream>>>(h, Wc, a_src, a_dst, z16, slog, dlog, N);
        int colbase = IN_DIM + HIDN * (l + 1);
        k_edge<<<8 * EDGE_SLOTS, 256, 0, stream>>>(cnt, payload2, slog, dlog, ea, z16,
                                                   h, out, colbase, N);
    }

    k_pool_partial<<<B * NSEGP, 256, 0, stream>>>(out, gpart);
    k_pool_final<<<(B * C1 + 3) / 4, 256, 0, stream>>>(gpart, gemb, B);
    k_bcast<<<((size_t)N * C1Q + 255) / 256, 256, 0, stream>>>(gemb, out, N);
}

// Round 13
// 251.425 us; speedup vs baseline: 18.5762x; 1.0096x over previous
//
#include <hip/hip_runtime.h>
#include <math.h>

#define IN_DIM 16
#define HIDN 128
#define NH 8
#define DHD 16
#define NTYPE 12
#define NLAYERS 4
#define NPG 5000
#define NSEGP 250
#define RPS (NPG / NSEGP)
#define C1 656
#define C2 1312
#define C1Q (C1 / 4)
#define CAP 64
#define NPW 4
#define HREG (NPG / 2)
#define GEMM_SLOTS ((HREG + 63) / 64)   // 40
#define EDGE_SLOTS (HREG / NPW)         // 625

__device__ __forceinline__ float gelu_t(float x) {
    float x3 = x * x * x;
    float u = 0.7978845608028654f * (x + 0.044715f * x3);
    return 0.5f * x * (1.0f + tanhf(u));
}

__device__ __forceinline__ unsigned pack_bf16(float lo, float hi) {
    unsigned a = __float_as_uint(lo);
    unsigned b = __float_as_uint(hi);
    a = (a + 0x7fffu + ((a >> 16) & 1u)) >> 16;
    b = (b + 0x7fffu + ((b >> 16) & 1u)) & 0xffff0000u;
    return a | b;
}

__device__ __forceinline__ float lrelu(float x) { return (x >= 0.f) ? x : 0.2f * x; }

// ---- init: ea table + zero bucket counters ----
__global__ __launch_bounds__(256) void k_init(const float* __restrict__ etab,
                                              const float* __restrict__ aed,
                                              float* __restrict__ ea, int* __restrict__ cnt,
                                              int N) {
    int i = blockIdx.x * 256 + threadIdx.x;
    if (i < NTYPE * NH) {
        int t = i / NH, hh = i % NH;
        float s = 0.f;
        #pragma unroll
        for (int d = 0; d < DHD; d++) s += etab[t * HIDN + hh * DHD + d] * aed[hh * DHD + d];
        ea[i] = s;
    }
    if (i < N) cnt[i] = 0;
}

// ---- pre: embed (wave-per-node) + edge bucketing, fused ----
__global__ __launch_bounds__(256) void k_pre(const float* __restrict__ feat,
                                             const float* __restrict__ We,
                                             const float* __restrict__ be,
                                             const int* __restrict__ srcp,
                                             const int* __restrict__ dstp,
                                             const int* __restrict__ etp,
                                             int* __restrict__ cnt,
                                             unsigned* __restrict__ payload2,
                                             float* __restrict__ out, int N, int E) {
    int bid = blockIdx.x, tid = threadIdx.x;
    int wave = tid >> 6, lane = tid & 63;
    // embed: 4 nodes per block
    int n = bid * NPW + wave;
    if (n < N) {
        float v = 0.f;
        if (lane < IN_DIM) {
            v = feat[n * IN_DIM + lane];
            if ((lane >= 2 && lane < 4) || lane >= 10) v = 0.f;
            out[(size_t)n * C2 + lane] = v;
        }
        float a0 = be[lane], a1 = be[lane + 64];
        #pragma unroll
        for (int k = 0; k < IN_DIM; k++) {
            float fk = __shfl(v, k);
            a0 += fk * We[k * HIDN + lane];
            a1 += fk * We[k * HIDN + lane + 64];
        }
        size_t ob = (size_t)n * C2 + IN_DIM;
        out[ob + lane] = gelu_t(a0);
        out[ob + lane + 64] = gelu_t(a1);
    }
    // bucket: grid-stride over edges
    for (int e = bid * 256 + tid; e < E; e += gridDim.x * 256) {
        int d = dstp[e];
        int slot = atomicAdd(&cnt[d], 1);
        if (slot < CAP)
            payload2[(size_t)d * CAP + slot] = (unsigned)srcp[e] | ((unsigned)etp[e] << 16);
    }
}

// ---- per-layer GEMM: reads prev cols of out; split-W LDS (2-way banks) ----
#define KC 64
__global__ __launch_bounds__(256) void k_gemm(const float* __restrict__ out,
                                              const float* __restrict__ W,
                                              const float* __restrict__ asf,
                                              const float* __restrict__ adf,
                                              unsigned* __restrict__ z16,
                                              float* __restrict__ slog,
                                              float* __restrict__ dlog, int prevbase, int N) {
    __shared__ float WcA[KC][64];   // cols 0-3 of each 8-block
    __shared__ float WcB[KC][64];   // cols 4-7 of each 8-block
    __shared__ float hc[64][KC + 4];
    int xcd = blockIdx.x & 7, slot = blockIdx.x >> 3;
    int g = xcd & 3, half = xcd >> 2;
    int base = g * NPG + half * HREG;
    int rend = base + HREG;
    int n0 = base + slot * 64;
    int t = threadIdx.x;
    int cg = t & 15, rg = t >> 4;
    int c0 = cg * 8;
    const float* hin = out + prevbase;
    float acc[4][8];
    #pragma unroll
    for (int i = 0; i < 4; i++)
        #pragma unroll
        for (int j = 0; j < 8; j++) acc[i][j] = 0.f;

    for (int k0 = 0; k0 < HIDN; k0 += KC) {
        for (int i = t; i < KC * 32; i += 256) {
            int kk = i >> 5, cc = (i & 31) << 2;
            float4 v = *(const float4*)&W[(k0 + kk) * HIDN + cc];
            int halfcol = (cc & ~4) >> 1;
            if (cc & 4) *(float4*)&WcB[kk][halfcol] = v;
            else *(float4*)&WcA[kk][halfcol] = v;
        }
        for (int i = t; i < 64 * (KC / 4); i += 256) {
            int rr = i / (KC / 4), kk = (i % (KC / 4)) * 4;
            int n = n0 + rr;
            float4 v = make_float4(0.f, 0.f, 0.f, 0.f);
            if (n < rend) v = *(const float4*)&hin[(size_t)n * C2 + k0 + kk];
            *(float4*)&hc[rr][kk] = v;
        }
        __syncthreads();
        for (int k = 0; k < KC; k++) {
            float4 w0 = *(float4*)&WcA[k][cg * 4];
            float4 w1 = *(float4*)&WcB[k][cg * 4];
            float hv[4];
            #pragma unroll
            for (int i = 0; i < 4; i++) hv[i] = hc[rg + 16 * i][k];
            #pragma unroll
            for (int i = 0; i < 4; i++) {
                acc[i][0] += hv[i] * w0.x;
                acc[i][1] += hv[i] * w0.y;
                acc[i][2] += hv[i] * w0.z;
                acc[i][3] += hv[i] * w0.w;
                acc[i][4] += hv[i] * w1.x;
                acc[i][5] += hv[i] * w1.y;
                acc[i][6] += hv[i] * w1.z;
                acc[i][7] += hv[i] * w1.w;
            }
        }
        __syncthreads();
    }
    float4 s0 = *(const float4*)&asf[c0];
    float4 s1 = *(const float4*)&asf[c0 + 4];
    float4 d0 = *(const float4*)&adf[c0];
    float4 d1 = *(const float4*)&adf[c0 + 4];
    #pragma unroll
    for (int i = 0; i < 4; i++) {
        int n = n0 + rg + 16 * i;
        float ps = acc[i][0] * s0.x + acc[i][1] * s0.y + acc[i][2] * s0.z + acc[i][3] * s0.w +
                   acc[i][4] * s1.x + acc[i][5] * s1.y + acc[i][6] * s1.z + acc[i][7] * s1.w;
        float pd = acc[i][0] * d0.x + acc[i][1] * d0.y + acc[i][2] * d0.z + acc[i][3] * d0.w +
                   acc[i][4] * d1.x + acc[i][5] * d1.y + acc[i][6] * d1.z + acc[i][7] * d1.w;
        ps += __shfl_xor(ps, 1);
        pd += __shfl_xor(pd, 1);
        unsigned u[8];
        #pragma unroll
        for (int j = 0; j < 8; j++) {
            float other = __shfl_xor(acc[i][j], 8);
            u[j] = pack_bf16(acc[i][j], other);
        }
        if (n < rend) {
            if (cg < 8) {
                *(uint4*)&z16[(size_t)n * 64 + c0] = make_uint4(u[0], u[1], u[2], u[3]);
                *(uint4*)&z16[(size_t)n * 64 + c0 + 4] = make_uint4(u[4], u[5], u[6], u[7]);
            }
            if ((cg & 1) == 0) {
                slog[n * NH + (cg >> 1)] = ps;
                dlog[n * NH + (cg >> 1)] = pd;
            }
        }
    }
}

// ---- per-layer edge aggregation: bucketed payload, out-resident residual ----
__global__ __launch_bounds__(256) void k_edge(const int* __restrict__ cnt,
                                              const unsigned* __restrict__ payload2,
                                              const float* __restrict__ slog,
                                              const float* __restrict__ dlog,
                                              const float* __restrict__ ea,
                                              const unsigned* __restrict__ z16,
                                              float* __restrict__ out, int prevbase,
                                              int curbase, int N) {
    int wave = threadIdx.x >> 6, lane = threadIdx.x & 63;
    int xcd = blockIdx.x & 7, slot = blockIdx.x >> 3;
    int g = xcd & 3, half = xcd >> 2;
    int unit = g * (NPG / NPW) + half * EDGE_SLOTS + slot;
    int n = unit * NPW + wave;
    bool active = (n < N);
    __shared__ float lbuf[NPW][CAP * NH];
    __shared__ unsigned pbuf[NPW][CAP];
    __shared__ float dl[NPW][NH];
    __shared__ float red[NPW][NH];
    __shared__ float sea[NTYPE * NH];

    if (threadIdx.x < NTYPE * NH) sea[threadIdx.x] = ea[threadIdx.x];

    int cntE = 0;
    if (active) {
        cntE = cnt[n];
        if (cntE > CAP) cntE = CAP;
        if (lane < NH) dl[wave][lane] = dlog[n * NH + lane];
    }
    if (lane < cntE) pbuf[wave][lane] = payload2[(size_t)n * CAP + lane];
    __syncthreads();

    int o = lane & 1;
    int eoff = lane >> 1;
    float4 dl4 = *(float4*)&dl[wave][o * 4];
    float4 ssum4 = make_float4(0.f, 0.f, 0.f, 0.f);
    #pragma unroll
    for (int base = 0; base < CAP; base += 32) {
        int el = base + eoff;
        if (el < cntE) {
            unsigned pk = pbuf[wave][el];
            int src = pk & 0xffff;
            int et = pk >> 16;
            float4 s4 = *(const float4*)&slog[src * NH + o * 4];
            float4 e4 = *(float4*)&sea[et * NH + o * 4];
            float4 ex;
            ex.x = __expf(lrelu(s4.x + dl4.x + e4.x));
            ex.y = __expf(lrelu(s4.y + dl4.y + e4.y));
            ex.z = __expf(lrelu(s4.z + dl4.z + e4.z));
            ex.w = __expf(lrelu(s4.w + dl4.w + e4.w));
            *(float4*)&lbuf[wave][el * NH + o * 4] = ex;
            ssum4.x += ex.x;
            ssum4.y += ex.y;
            ssum4.z += ex.z;
            ssum4.w += ex.w;
        }
    }
    #pragma unroll
    for (int m = 2; m <= 32; m <<= 1) {
        ssum4.x += __shfl_xor(ssum4.x, m);
        ssum4.y += __shfl_xor(ssum4.y, m);
        ssum4.z += __shfl_xor(ssum4.z, m);
        ssum4.w += __shfl_xor(ssum4.w, m);
    }
    if (lane < 2) {
        float4 r4;
        r4.x = 1.0f / (ssum4.x + 1e-9f);
        r4.y = 1.0f / (ssum4.y + 1e-9f);
        r4.z = 1.0f / (ssum4.z + 1e-9f);
        r4.w = 1.0f / (ssum4.w + 1e-9f);
        *(float4*)&red[wave][o * 4] = r4;
    }
    __syncthreads();

    int h1 = lane >> 4, h2 = h1 + 4;
    float r1 = red[wave][h1], r2 = red[wave][h2];
    float a0 = 0.f, a1 = 0.f;
    int e = 0;
    for (; e + 7 < cntE; e += 8) {
        unsigned v[8];
        #pragma unroll
        for (int j = 0; j < 8; j++) {
            unsigned s = pbuf[wave][e + j] & 0xffff;
            v[j] = z16[(size_t)s * 64 + lane];
        }
        #pragma unroll
        for (int j = 0; j < 8; j++) {
            float l0 = lbuf[wave][(e + j) * NH + h1];
            float l1 = lbuf[wave][(e + j) * NH + h2];
            a0 += l0 * __uint_as_float(v[j] << 16);
            a1 += l1 * __uint_as_float(v[j] & 0xffff0000u);
        }
    }
    for (; e < cntE; e++) {
        unsigned s0 = pbuf[wave][e] & 0xffff;
        unsigned v0 = z16[(size_t)s0 * 64 + lane];
        a0 += lbuf[wave][e * NH + h1] * __uint_as_float(v0 << 16);
        a1 += lbuf[wave][e * NH + h2] * __uint_as_float(v0 & 0xffff0000u);
    }
    if (active) {
        a0 *= r1;
        a1 *= r2;
        size_t rowb = (size_t)n * C2;
        float o0 = out[rowb + prevbase + lane] + gelu_t(a0);
        float o1 = out[rowb + prevbase + lane + 64] + gelu_t(a1);
        out[rowb + curbase + lane] = o0;
        out[rowb + curbase + lane + 64] = o1;
    }
}

// ---- graph max-pool: XCD-region-mapped partial ----
__global__ __launch_bounds__(256) void k_pool_partial(const float* __restrict__ out,
                                                      float* __restrict__ gpart) {
    int xcd = blockIdx.x & 7, slot = blockIdx.x >> 3;   // slot 0..124
    int b = xcd & 3, half = xcd >> 2;
    int seg = half * (NSEGP / 2) + slot;
    int n0 = b * NPG + seg * RPS;
    for (int c = threadIdx.x; c < C1; c += 256) {
        float m = -3.4e38f;
        #pragma unroll
        for (int i = 0; i < RPS; i++) m = fmaxf(m, out[(size_t)(n0 + i) * C2 + c]);
        gpart[(size_t)(b * NSEGP + seg) * C1 + c] = m;
    }
}

__global__ __launch_bounds__(256) void k_pool_final(const float* __restrict__ gpart,
                                                    float* __restrict__ gemb, int B) {
    int w = blockIdx.x * 4 + (threadIdx.x >> 6);
    int lane = threadIdx.x & 63;
    if (w >= B * C1) return;
    int b = w / C1, c = w % C1;
    float m = -3.4e38f;
    for (int s = lane; s < NSEGP; s += 64) m = fmaxf(m, gpart[(size_t)(b * NSEGP + s) * C1 + c]);
    #pragma unroll
    for (int k = 1; k < 64; k <<= 1) m = fmaxf(m, __shfl_xor(m, k));
    if (lane == 0) gemb[w] = m;
}

__global__ __launch_bounds__(256) void k_bcast(const float* __restrict__ gemb,
                                               float* __restrict__ out, int N) {
    int idx = blockIdx.x * 256 + threadIdx.x;
    if (idx < N * C1Q) {
        int n = idx / C1Q, c4 = idx % C1Q;
        int b = n / NPG;
        float4 g = *(const float4*)&gemb[b * C1 + c4 * 4];
        *(float4*)&out[(size_t)n * C2 + C1 + c4 * 4] = g;
    }
}

extern "C" void kernel_launch(void* const* d_in, const int* in_sizes, int n_in, void* d_out,
                              int out_size, void* d_ws, size_t ws_size, hipStream_t stream) {
    const float* feat = (const float*)d_in[0];
    const float* etab = (const float*)d_in[1];
    const float* We = (const float*)d_in[2];
    const float* be = (const float*)d_in[3];
    const float* Wc = (const float*)d_in[4];
    const float* a_src = (const float*)d_in[5];
    const float* a_dst = (const float*)d_in[6];
    const float* a_edge = (const float*)d_in[7];
    const int* eidx = (const int*)d_in[8];
    const int* etype = (const int*)d_in[9];
    float* out = (float*)d_out;

    const int N = in_sizes[0] / IN_DIM;   // 20000
    const int E = in_sizes[9];            // 660000
    const int B = N / NPG;                // 4

    const int* srcp = eidx;
    const int* dstp = eidx + E;

    char* w = (char*)d_ws;
    size_t off = 0;
    auto carve = [&](size_t bytes) {
        char* p = w + off;
        off = (off + bytes + 255) & ~(size_t)255;
        return p;
    };
    unsigned* z16 = (unsigned*)carve((size_t)N * 64 * 4);
    float* slog = (float*)carve((size_t)N * NH * 4);
    float* dlog = (float*)carve((size_t)N * NH * 4);
    float* ea = (float*)carve(NTYPE * NH * 4);
    int* cnt = (int*)carve((size_t)N * 4);
    unsigned* payload2 = (unsigned*)carve((size_t)N * CAP * 4);
    float* gpart = (float*)carve((size_t)B * NSEGP * C1 * 4);
    float* gemb = (float*)carve((size_t)B * C1 * 4);
    (void)ws_size;

    k_init<<<(N + 255) / 256, 256, 0, stream>>>(etab, a_edge, ea, cnt, N);
    k_pre<<<(N + NPW - 1) / NPW, 256, 0, stream>>>(feat, We, be, srcp, dstp, etype, cnt,
                                                   payload2, out, N, E);

    for (int l = 0; l < NLAYERS; l++) {
        int prevbase = IN_DIM + HIDN * l;
        int curbase = IN_DIM + HIDN * (l + 1);
        k_gemm<<<8 * GEMM_SLOTS, 256, 0, stream>>>(out, Wc, a_src, a_dst, z16, slog, dlog,
                                                   prevbase, N);
        k_edge<<<8 * EDGE_SLOTS, 256, 0, stream>>>(cnt, payload2, slog, dlog, ea, z16, out,
                                                   prevbase, curbase, N);
    }

    k_pool_partial<<<8 * (NSEGP / 2), 256, 0, stream>>>(out, gpart);
    k_pool_final<<<(B * C1 + 3) / 4, 256, 0, stream>>>(gpart, gemb, B);
    k_bcast<<<((size_t)N * C1Q + 255) / 256, 256, 0, stream>>>(gemb, out, N);
}